// Round 9
// baseline (503.380 us; speedup 1.0000x reference)
//
#include <hip/hip_runtime.h>

typedef float  f32x4 __attribute__((ext_vector_type(4)));
typedef short  s16x8 __attribute__((ext_vector_type(8)));
typedef short  s16x4 __attribute__((ext_vector_type(4)));
typedef int    i32x4 __attribute__((ext_vector_type(4)));

#define MFMA16(a,b,c) __builtin_amdgcn_mfma_f32_16x16x32_bf16(a,b,c,0,0,0)

static __device__ __forceinline__ f32x4 mfma_pv(s16x4 a, s16x4 b, f32x4 c){
#if defined(__HIP_DEVICE_COMPILE__)
    return __builtin_amdgcn_mfma_f32_16x16x16bf16_1k(a, b, c, 0, 0, 0);
#else
    (void)a; (void)b; return c;
#endif
}

// async global->LDS, 16B per lane: data lands at lds_base(wave-uniform)+lane*16
static __device__ __forceinline__ void glds16(const void* g, void* l){
#if defined(__HIP_DEVICE_COMPILE__)
    __builtin_amdgcn_global_load_lds(
        (const __attribute__((address_space(1))) unsigned int*)g,
        (__attribute__((address_space(3))) unsigned int*)l, 16, 0, 0);
#else
    (void)g; (void)l;
#endif
}

// nontemporal int4 load: one-pass streams (mask) must NOT allocate in L2/L3 --
// the 268MB raw mask ~= L3 size and was evicting the K/V panels (R7 proof:
// removing the stream cut attn FETCH 170->41MB).
static __device__ __forceinline__ i32x4 ntload4(const int* p){
#if __has_builtin(__builtin_nontemporal_load)
    return __builtin_nontemporal_load((const i32x4*)p);
#else
    return *(const i32x4*)p;
#endif
}
static __device__ __forceinline__ void ntstoref(float v, float* p){
#if __has_builtin(__builtin_nontemporal_store)
    __builtin_nontemporal_store(v, p);
#else
    *p = v;
#endif
}

// B=4, N1=N2=4096, D=H=256. Inputs fp32, output fp32.
static __device__ __forceinline__ unsigned short f2bf(float f){
    union { float f; unsigned int u; } x; x.f = f;
    unsigned int r = x.u + 0x7fffu + ((x.u >> 16) & 1u);   // RNE
    return (unsigned short)(r >> 16);
}

// ---------------- kernel 1: W^T -> bf16, MFMA B-frag order ----------------
__global__ void wt_prep(const float* __restrict__ Wq, const float* __restrict__ Wk,
                        const float* __restrict__ Wv, unsigned short* __restrict__ wt){
    const int p = blockIdx.y;
    const int o8 = blockIdx.x*256 + threadIdx.x;       // [0, 8192)
    const float* W = (p==0) ? Wq : ((p==1) ? Wk : Wv);
    const int lane = o8 & 63, t = (o8 >> 6) & 15, ks = o8 >> 10;
    const int quad = lane >> 4, lq = lane & 15;
    s16x8 o;
    #pragma unroll
    for(int j=0;j<8;j++)
        o[j] = (short)f2bf(W[(ks*32 + quad*8 + j)*256 + 16*t + lq]);
    *(s16x8*)(wt + (size_t)p*65536 + (size_t)o8*8) = o;
}

// -------- staging helper: x tile (64x256 fp32) -> bf16 LDS (stride 264) ------
static __device__ __forceinline__ void stage_x(const float* x, size_t row0,
                                               int tid, unsigned short* sX){
    const float* xg = x + row0*256;
    #pragma unroll
    for(int rr=0; rr<16; rr++){
        int c = tid + rr*256;
        int row = c>>6, cc = c&63;
        float4 f = *(const float4*)(xg + row*256 + cc*4);
        unsigned short* d = &sX[row*264 + cc*4];
        d[0]=f2bf(f.x); d[1]=f2bf(f.y); d[2]=f2bf(f.z); d[3]=f2bf(f.w);
    }
}

// ---------------- kernel 2: ALL projections, one launch ----------------------
__global__ __launch_bounds__(256) void proj_all(const float* __restrict__ x1,
        const float* __restrict__ x2, const unsigned short* __restrict__ wt,
        const float* __restrict__ bq, const float* __restrict__ bk,
        const float* __restrict__ bv, int b0,
        unsigned short* __restrict__ qdst, unsigned short* __restrict__ kfrag,
        unsigned short* __restrict__ vfrag){
    const int rt = blockIdx.x, p = blockIdx.y, z = blockIdx.z;
    const int zz = b0 + z;
    const int tid = threadIdx.x, w = tid>>6, lane = tid&63, quad = lane>>4, lq = lane&15;
    __shared__ __align__(16) unsigned short sX[64*264];

    const float* x = (p==0) ? x1 : x2;
    stage_x(x, (size_t)(zz*64 + rt)*64, tid, sX);
    __syncthreads();

    s16x8 a[8];
    #pragma unroll
    for(int ks=0; ks<8; ks++)
        a[ks] = *(const s16x8*)(&sX[(16*w+lq)*264 + ks*32 + quad*8]);

    f32x4 acc[16];
    #pragma unroll
    for(int t=0;t<16;t++) acc[t] = (f32x4)(0.0f);
    const unsigned short* wtp = wt + (size_t)p*65536;
    #pragma unroll
    for(int ks=0; ks<8; ks++){
        #pragma unroll
        for(int t=0; t<16; t++){
            s16x8 bf_ = *(const s16x8*)(wtp + (((size_t)(ks*16 + t)*64 + lane)*8));
            acc[t] = MFMA16(a[ks], bf_, acc[t]);
        }
    }

    if(p == 0){          // Q row-major
        #pragma unroll
        for(int t=0;t<16;t++){
            float bvf = bq[16*t+lq];
            #pragma unroll
            for(int r=0;r<4;r++){
                size_t row = (size_t)(zz*64 + rt)*64 + 16*w + 4*quad + r;
                qdst[row*256 + 16*t + lq] = f2bf(acc[t][r] + bvf);
            }
        }
    } else if(p == 1){   // K -> kfrag via LDS round-trip
        __syncthreads();
        #pragma unroll
        for(int t=0;t<16;t++){
            float bvf = bk[16*t+lq];
            #pragma unroll
            for(int r=0;r<4;r++)
                sX[(16*w + 4*quad + r)*264 + 16*t + lq] = f2bf(acc[t][r] + bvf);
        }
        __syncthreads();
        unsigned short* kd = kfrag + (size_t)z*1048576;
        #pragma unroll
        for(int ks=0; ks<8; ks++){
            s16x8 v = *(const s16x8*)(&sX[(16*w + lq)*264 + 32*ks + 8*quad]);
            *(s16x8*)(kd + ((((size_t)rt*4 + w)*8 + ks)*64 + lane)*8) = v;
        }
    } else {             // V -> vfrag direct
        unsigned short* vd = vfrag + (size_t)z*1048576;
        #pragma unroll
        for(int t2=0; t2<8; t2++){
            float b0f = bv[16*(2*t2  )+lq];
            float b1f = bv[16*(2*t2+1)+lq];
            s16x8 o;
            #pragma unroll
            for(int r=0;r<4;r++){
                o[r]   = (short)f2bf(acc[2*t2  ][r] + b0f);
                o[4+r] = (short)f2bf(acc[2*t2+1][r] + b1f);
            }
            *(s16x8*)(vd + ((((size_t)rt*4 + w)*8 + t2)*64 + lane)*8) = o;
        }
    }
}

// ---------------- kernel 3: flash attn, counted-vmcnt double-buffer ----------
// R8 structure + T3/T4 counted wait. Per body:
//   [s_waitcnt vmcnt(2); s_barrier]  <- retires the 8 staging glds (issued one
//                                       body ago), LEAVES the 2 nt mask loads
//                                       outstanding (they're pure-HBM; the old
//                                       __syncthreads vmcnt(0) drained them =>
//                                       per-iter HBM latency on critical path)
//   glds(kt+1) x8 into buf^1         <- top-of-body issue, ~full body in flight
//   S^T MFMAs / exp(mask) / PV       <- compiler auto-inserts counted vmcnt(8)
//                                       for the mask regs before exp (no drain)
//   sched_barrier(0); mask(kt+1) x2  <- bottom issue + fence guarantees the
//                                       invariant "glds older than masks", so
//                                       vmcnt(2) at next body-top is exact.
// Prologue establishes the same queue shape: [Q..., glds x8, FENCE, mask x2,
// FENCE]. Epilogue unchanged (aliases buf0; nothing outstanding by then).
__global__ __launch_bounds__(512,2) void attn(
        const unsigned short* __restrict__ qb, const unsigned short* __restrict__ kfrag,
        const unsigned short* __restrict__ vfrag, const int* __restrict__ mask,
        float* __restrict__ out, int b0){
    const int bid = blockIdx.x;
    int b, qt, bk_;
    if(gridDim.x == 256){ b = (bid&7)>>1; qt = (bid>>3)*2 + (bid&1); bk_ = b; }
    else                { b = b0; qt = bid; bk_ = 0; }
    const int tid = threadIdx.x, w4 = tid>>6, lane = tid&63, quad = lane>>4, lq = lane&15;
    const int qg = w4>>2, w = w4&3;
    const int qbase = qt*64 + 32*qg;

    __shared__ __align__(16) unsigned char smem[131072];

    // Q as B-operand frags (rows qbase+16rg+lq)
    s16x8 qf[2][8];
    #pragma unroll
    for(int rg=0; rg<2; rg++){
        size_t row = (size_t)(b*4096 + qbase + 16*rg + lq);
        #pragma unroll
        for(int ks=0; ks<8; ks++)
            qf[rg][ks] = *(const s16x8*)(qb + row*256 + ks*32 + quad*8);
    }

    f32x4 oacc[16][2];                 // O^T partial: h=16t+4quad+r, q=16rg+lq
    #pragma unroll
    for(int t=0;t<16;t++){ oacc[t][0] = (f32x4)(0.0f); oacc[t][1] = (f32x4)(0.0f); }
    float rsum[2] = {0.0f, 0.0f};

    const unsigned char* kfb = (const unsigned char*)(kfrag + (size_t)bk_*1048576);
    const unsigned char* vfb = (const unsigned char*)(vfrag + (size_t)bk_*1048576);
    const int* mp0 = mask + ((size_t)(b*4096 + qbase) + lq)*4096 + 16*w + 4*quad;
    const unsigned lsl = w4*1024 + lane*16;   // per-lane global offset within 8KB round
    const unsigned ldd = w4*1024;             // wave-uniform LDS offset

    // ---- prologue: stage kt=0, then mask kt=0 as the NEWEST 2 vmem ops ----
    #pragma unroll
    for(int r=0; r<4; r++){
        glds16(kfb + r*8192 + lsl, smem + r*8192 + ldd);
        glds16(vfb + r*8192 + lsl, smem + 32768 + r*8192 + ldd);
    }
    __builtin_amdgcn_sched_barrier(0);
    i32x4 mA0 = ntload4(mp0);
    i32x4 mA1 = ntload4(mp0 + (size_t)16*4096);
    __builtin_amdgcn_sched_barrier(0);

    for(int kt=0; kt<64; kt++){
        const int cb = kt & 1;
        // counted wait: staging retired, masks stay in flight
        asm volatile("s_waitcnt vmcnt(2)" ::: "memory");
        __builtin_amdgcn_s_barrier();

        // ---- stage kt+1 into the other buffer (top issue, full-body slack) ----
        if(kt < 63){
            const unsigned char* gK = kfb + (size_t)(kt+1)*32768;
            const unsigned char* gV = vfb + (size_t)(kt+1)*32768;
            unsigned char* dst = smem + (cb^1)*65536;
            #pragma unroll
            for(int r=0; r<4; r++){
                glds16(gK + r*8192 + lsl, dst + r*8192 + ldd);
                glds16(gV + r*8192 + lsl, dst + 32768 + r*8192 + ldd);
            }
        }
        const unsigned short* bK = (const unsigned short*)(smem + cb*65536);
        const unsigned short* bV = (const unsigned short*)(smem + cb*65536 + 32768);

        // ---- S^T: D[n2local=4quad+r][q=lq] ----
        f32x4 sacc0 = (f32x4)(0.0f), sacc1 = (f32x4)(0.0f);
        #pragma unroll
        for(int ks=0; ks<8; ks++){
            s16x8 kf = *(const s16x8*)(bK + ((w*8 + ks)*64 + lane)*8);
            sacc0 = MFMA16(kf, qf[0][ks], sacc0);
            sacc1 = MFMA16(kf, qf[1][ks], sacc1);
        }
        // ---- mask + exp + pack (C rows 4quad+r == PV k=4quad+j) ----
        s16x4 pb0, pb1;
        {
            float p;
            p = (mA0.x>0)?__expf(sacc0[0]*0.0625f):1.0f; rsum[0]+=p; pb0[0]=(short)f2bf(p);
            p = (mA0.y>0)?__expf(sacc0[1]*0.0625f):1.0f; rsum[0]+=p; pb0[1]=(short)f2bf(p);
            p = (mA0.z>0)?__expf(sacc0[2]*0.0625f):1.0f; rsum[0]+=p; pb0[2]=(short)f2bf(p);
            p = (mA0.w>0)?__expf(sacc0[3]*0.0625f):1.0f; rsum[0]+=p; pb0[3]=(short)f2bf(p);
            p = (mA1.x>0)?__expf(sacc1[0]*0.0625f):1.0f; rsum[1]+=p; pb1[0]=(short)f2bf(p);
            p = (mA1.y>0)?__expf(sacc1[1]*0.0625f):1.0f; rsum[1]+=p; pb1[1]=(short)f2bf(p);
            p = (mA1.z>0)?__expf(sacc1[2]*0.0625f):1.0f; rsum[1]+=p; pb1[2]=(short)f2bf(p);
            p = (mA1.w>0)?__expf(sacc1[3]*0.0625f):1.0f; rsum[1]+=p; pb1[3]=(short)f2bf(p);
        }
        // ---- PV ----
        #pragma unroll
        for(int t2=0; t2<8; t2++){
            s16x8 vv = *(const s16x8*)(bV + ((w*8 + t2)*64 + lane)*8);
            s16x4 vlo = __builtin_shufflevector(vv, vv, 0,1,2,3);
            s16x4 vhi = __builtin_shufflevector(vv, vv, 4,5,6,7);
            oacc[2*t2  ][0] = mfma_pv(vlo, pb0, oacc[2*t2  ][0]);
            oacc[2*t2  ][1] = mfma_pv(vlo, pb1, oacc[2*t2  ][1]);
            oacc[2*t2+1][0] = mfma_pv(vhi, pb0, oacc[2*t2+1][0]);
            oacc[2*t2+1][1] = mfma_pv(vhi, pb1, oacc[2*t2+1][1]);
        }
        // ---- bottom: mask kt+1 (newest vmem ops; fence keeps them newest) ----
        if(kt < 63){
            __builtin_amdgcn_sched_barrier(0);
            mA0 = ntload4(mp0 + (size_t)(kt+1)*64);
            mA1 = ntload4(mp0 + (size_t)16*4096 + (kt+1)*64);
        }
    }

    // ---- epilogue: alias buf0 region (safe: buf0 last read kt=62; all waves
    // past kt=63's barrier) ----
    float* sRS  = (float*)smem;              // [8][32]
    float* sRed = (float*)(smem + 1024);     // [4][2081]
    #pragma unroll
    for(int rg=0; rg<2; rg++){
        float v = rsum[rg];
        v += __shfl_xor(v, 16);
        v += __shfl_xor(v, 32);
        if(quad == 0) sRS[(qg*4 + w)*32 + 16*rg + lq] = v;
    }
    for(int g=0; g<2; g++){
        for(int c=0; c<4; c++){
            __syncthreads();
            if(qg == g){
                #pragma unroll
                for(int tt=0; tt<4; tt++){
                    int t = 4*c + tt;
                    #pragma unroll
                    for(int rg=0; rg<2; rg++){
                        #pragma unroll
                        for(int r=0; r<4; r++)
                            sRed[w*2081 + (16*rg+lq)*65 + 16*tt + 4*quad + r] = oacc[t][rg][r];
                    }
                }
            }
            __syncthreads();
            #pragma unroll
            for(int j=0; j<4; j++){
                int idx = j*512 + tid;
                int hl = idx & 63, q = idx >> 6;
                float s  = sRed[0*2081 + q*65+hl] + sRed[1*2081 + q*65+hl]
                         + sRed[2*2081 + q*65+hl] + sRed[3*2081 + q*65+hl];
                float rs = sRS[(g*4+0)*32+q] + sRS[(g*4+1)*32+q]
                         + sRS[(g*4+2)*32+q] + sRS[(g*4+3)*32+q];
                ntstoref(s / rs,
                    &out[((size_t)(b*4096 + qt*64 + 32*g + q))*256 + 64*c + hl]);
            }
        }
    }
}

extern "C" void kernel_launch(void* const* d_in, const int* in_sizes, int n_in,
                              void* d_out, int out_size, void* d_ws, size_t ws_size,
                              hipStream_t stream){
    (void)in_sizes; (void)n_in; (void)out_size;
    const float* x1 = (const float*)d_in[0];
    const float* x2 = (const float*)d_in[1];
    const int*   mk = (const int*)  d_in[2];
    const float* Wq = (const float*)d_in[3];
    const float* bq = (const float*)d_in[4];
    const float* Wk = (const float*)d_in[5];
    const float* bk = (const float*)d_in[6];
    const float* Wv = (const float*)d_in[7];
    const float* bv = (const float*)d_in[8];
    float* out = (float*)d_out;
    char* ws = (char*)d_ws;

    // ws layout: wt 384K @0 | q 8M | kfrag | vfrag
    unsigned short* wt = (unsigned short*)ws;
    unsigned short* qb = (unsigned short*)(ws + 393216);
    const size_t kvoff = 393216 + 8388608;

    wt_prep<<<dim3(32,3), 256, 0, stream>>>(Wq, Wk, Wv, wt);

    if(ws_size >= kvoff + 16ull*1024*1024){
        unsigned short* kf = (unsigned short*)(ws + kvoff);
        unsigned short* vf = (unsigned short*)(ws + kvoff + 8388608);
        proj_all<<<dim3(64,3,4), 256, 0, stream>>>(x1, x2, wt, bq, bk, bv, 0,
                                                   qb, kf, vf);
        attn<<<256, 512, 0, stream>>>(qb, kf, vf, mk, out, 0);
    } else {
        unsigned short* kf = (unsigned short*)(ws + kvoff);
        unsigned short* vf = (unsigned short*)(ws + kvoff + 2097152);
        for(int b=0;b<4;b++){
            proj_all<<<dim3(64,3,1), 256, 0, stream>>>(x1, x2, wt, bq, bk, bv, b,
                                                       qb, kf, vf);
            attn<<<64, 512, 0, stream>>>(qb, kf, vf, mk, out, b);
        }
    }
}

// Round 10
// 497.794 us; speedup vs baseline: 1.0112x; 1.0112x over previous
//
#include <hip/hip_runtime.h>

typedef float  f32x4 __attribute__((ext_vector_type(4)));
typedef short  s16x8 __attribute__((ext_vector_type(8)));
typedef short  s16x4 __attribute__((ext_vector_type(4)));
typedef int    i32x4 __attribute__((ext_vector_type(4)));

#define MFMA16(a,b,c) __builtin_amdgcn_mfma_f32_16x16x32_bf16(a,b,c,0,0,0)

static __device__ __forceinline__ f32x4 mfma_pv(s16x4 a, s16x4 b, f32x4 c){
#if defined(__HIP_DEVICE_COMPILE__)
    return __builtin_amdgcn_mfma_f32_16x16x16bf16_1k(a, b, c, 0, 0, 0);
#else
    (void)a; (void)b; return c;
#endif
}

// async global->LDS, 16B per lane: data lands at lds_base(wave-uniform)+lane*16
static __device__ __forceinline__ void glds16(const void* g, void* l){
#if defined(__HIP_DEVICE_COMPILE__)
    __builtin_amdgcn_global_load_lds(
        (const __attribute__((address_space(1))) unsigned int*)g,
        (__attribute__((address_space(3))) unsigned int*)l, 16, 0, 0);
#else
    (void)g; (void)l;
#endif
}

// nontemporal int4 load: one-pass streams (mask) must NOT allocate in L2/L3 --
// the 268MB raw mask ~= L3 size and was evicting the K/V panels (R7 proof:
// removing the stream cut attn FETCH 170->41MB).
static __device__ __forceinline__ i32x4 ntload4(const int* p){
#if __has_builtin(__builtin_nontemporal_load)
    return __builtin_nontemporal_load((const i32x4*)p);
#else
    return *(const i32x4*)p;
#endif
}
static __device__ __forceinline__ void ntstoref(float v, float* p){
#if __has_builtin(__builtin_nontemporal_store)
    __builtin_nontemporal_store(v, p);
#else
    *p = v;
#endif
}

// B=4, N1=N2=4096, D=H=256. Inputs fp32, output fp32.
static __device__ __forceinline__ unsigned short f2bf(float f){
    union { float f; unsigned int u; } x; x.f = f;
    unsigned int r = x.u + 0x7fffu + ((x.u >> 16) & 1u);   // RNE
    return (unsigned short)(r >> 16);
}

// ---------------- kernel 1: W^T -> bf16, MFMA B-frag order ----------------
__global__ void wt_prep(const float* __restrict__ Wq, const float* __restrict__ Wk,
                        const float* __restrict__ Wv, unsigned short* __restrict__ wt){
    const int p = blockIdx.y;
    const int o8 = blockIdx.x*256 + threadIdx.x;       // [0, 8192)
    const float* W = (p==0) ? Wq : ((p==1) ? Wk : Wv);
    const int lane = o8 & 63, t = (o8 >> 6) & 15, ks = o8 >> 10;
    const int quad = lane >> 4, lq = lane & 15;
    s16x8 o;
    #pragma unroll
    for(int j=0;j<8;j++)
        o[j] = (short)f2bf(W[(ks*32 + quad*8 + j)*256 + 16*t + lq]);
    *(s16x8*)(wt + (size_t)p*65536 + (size_t)o8*8) = o;
}

// -------- staging helper: x tile (64x256 fp32) -> bf16 LDS (stride 264) ------
static __device__ __forceinline__ void stage_x(const float* x, size_t row0,
                                               int tid, unsigned short* sX){
    const float* xg = x + row0*256;
    #pragma unroll
    for(int rr=0; rr<16; rr++){
        int c = tid + rr*256;
        int row = c>>6, cc = c&63;
        float4 f = *(const float4*)(xg + row*256 + cc*4);
        unsigned short* d = &sX[row*264 + cc*4];
        d[0]=f2bf(f.x); d[1]=f2bf(f.y); d[2]=f2bf(f.z); d[3]=f2bf(f.w);
    }
}

// ---------------- kernel 2: ALL projections, one launch ----------------------
__global__ __launch_bounds__(256) void proj_all(const float* __restrict__ x1,
        const float* __restrict__ x2, const unsigned short* __restrict__ wt,
        const float* __restrict__ bq, const float* __restrict__ bk,
        const float* __restrict__ bv, int b0,
        unsigned short* __restrict__ qdst, unsigned short* __restrict__ kfrag,
        unsigned short* __restrict__ vfrag){
    const int rt = blockIdx.x, p = blockIdx.y, z = blockIdx.z;
    const int zz = b0 + z;
    const int tid = threadIdx.x, w = tid>>6, lane = tid&63, quad = lane>>4, lq = lane&15;
    __shared__ __align__(16) unsigned short sX[64*264];

    const float* x = (p==0) ? x1 : x2;
    stage_x(x, (size_t)(zz*64 + rt)*64, tid, sX);
    __syncthreads();

    s16x8 a[8];
    #pragma unroll
    for(int ks=0; ks<8; ks++)
        a[ks] = *(const s16x8*)(&sX[(16*w+lq)*264 + ks*32 + quad*8]);

    f32x4 acc[16];
    #pragma unroll
    for(int t=0;t<16;t++) acc[t] = (f32x4)(0.0f);
    const unsigned short* wtp = wt + (size_t)p*65536;
    #pragma unroll
    for(int ks=0; ks<8; ks++){
        #pragma unroll
        for(int t=0; t<16; t++){
            s16x8 bf_ = *(const s16x8*)(wtp + (((size_t)(ks*16 + t)*64 + lane)*8));
            acc[t] = MFMA16(a[ks], bf_, acc[t]);
        }
    }

    if(p == 0){          // Q row-major
        #pragma unroll
        for(int t=0;t<16;t++){
            float bvf = bq[16*t+lq];
            #pragma unroll
            for(int r=0;r<4;r++){
                size_t row = (size_t)(zz*64 + rt)*64 + 16*w + 4*quad + r;
                qdst[row*256 + 16*t + lq] = f2bf(acc[t][r] + bvf);
            }
        }
    } else if(p == 1){   // K -> kfrag via LDS round-trip
        __syncthreads();
        #pragma unroll
        for(int t=0;t<16;t++){
            float bvf = bk[16*t+lq];
            #pragma unroll
            for(int r=0;r<4;r++)
                sX[(16*w + 4*quad + r)*264 + 16*t + lq] = f2bf(acc[t][r] + bvf);
        }
        __syncthreads();
        unsigned short* kd = kfrag + (size_t)z*1048576;
        #pragma unroll
        for(int ks=0; ks<8; ks++){
            s16x8 v = *(const s16x8*)(&sX[(16*w + lq)*264 + 32*ks + 8*quad]);
            *(s16x8*)(kd + ((((size_t)rt*4 + w)*8 + ks)*64 + lane)*8) = v;
        }
    } else {             // V -> vfrag direct
        unsigned short* vd = vfrag + (size_t)z*1048576;
        #pragma unroll
        for(int t2=0; t2<8; t2++){
            float b0f = bv[16*(2*t2  )+lq];
            float b1f = bv[16*(2*t2+1)+lq];
            s16x8 o;
            #pragma unroll
            for(int r=0;r<4;r++){
                o[r]   = (short)f2bf(acc[2*t2  ][r] + b0f);
                o[4+r] = (short)f2bf(acc[2*t2+1][r] + b1f);
            }
            *(s16x8*)(vd + ((((size_t)rt*4 + w)*8 + t2)*64 + lane)*8) = o;
        }
    }
}

// ---------------- kernel 3: flash attn, async-LDS double-buffered ------------
// Best verified variant (R8, 497.5us total): 512 thr = 8 waves, TM=64 q-rows,
// 2 x 64KB LDS buffers (K 32KB + V 32KB, frag order). At top of body kt, right
// after the barrier, issue the mask prefetch (kt+1, reg dbuf) and the async
// stage of kt+1 into buf[cb^1]; both have the full body in flight before the
// next barrier's vmcnt(0) drain. Mask loads are NONTEMPORAL: the 268MB mask
// stream (~= L3 size) otherwise evicts the K/V panels from L2/L3, putting the
// staging drain at HBM latency (R5/R7 evidence). Output stores nontemporal.
// R9's counted-vmcnt variant measured neutral-to-negative (masks were not on
// the critical path; the sched fences cost more than the drain) -- reverted.
__global__ __launch_bounds__(512,2) void attn(
        const unsigned short* __restrict__ qb, const unsigned short* __restrict__ kfrag,
        const unsigned short* __restrict__ vfrag, const int* __restrict__ mask,
        float* __restrict__ out, int b0){
    const int bid = blockIdx.x;
    int b, qt, bk_;
    if(gridDim.x == 256){ b = (bid&7)>>1; qt = (bid>>3)*2 + (bid&1); bk_ = b; }
    else                { b = b0; qt = bid; bk_ = 0; }
    const int tid = threadIdx.x, w4 = tid>>6, lane = tid&63, quad = lane>>4, lq = lane&15;
    const int qg = w4>>2, w = w4&3;
    const int qbase = qt*64 + 32*qg;

    __shared__ __align__(16) unsigned char smem[131072];

    // Q as B-operand frags (rows qbase+16rg+lq)
    s16x8 qf[2][8];
    #pragma unroll
    for(int rg=0; rg<2; rg++){
        size_t row = (size_t)(b*4096 + qbase + 16*rg + lq);
        #pragma unroll
        for(int ks=0; ks<8; ks++)
            qf[rg][ks] = *(const s16x8*)(qb + row*256 + ks*32 + quad*8);
    }

    f32x4 oacc[16][2];                 // O^T partial: h=16t+4quad+r, q=16rg+lq
    #pragma unroll
    for(int t=0;t<16;t++){ oacc[t][0] = (f32x4)(0.0f); oacc[t][1] = (f32x4)(0.0f); }
    float rsum[2] = {0.0f, 0.0f};

    const unsigned char* kfb = (const unsigned char*)(kfrag + (size_t)bk_*1048576);
    const unsigned char* vfb = (const unsigned char*)(vfrag + (size_t)bk_*1048576);
    const int* mp0 = mask + ((size_t)(b*4096 + qbase) + lq)*4096 + 16*w + 4*quad;
    const unsigned lsl = w4*1024 + lane*16;   // per-lane global offset within 8KB round
    const unsigned ldd = w4*1024;             // wave-uniform LDS offset

    // prologue: mask kt=0 into regs (nt), stage kt=0 into buf0
    i32x4 mA0 = ntload4(mp0);
    i32x4 mA1 = ntload4(mp0 + (size_t)16*4096);
    #pragma unroll
    for(int r=0; r<4; r++){
        glds16(kfb + r*8192 + lsl, smem + r*8192 + ldd);
        glds16(vfb + r*8192 + lsl, smem + 32768 + r*8192 + ldd);
    }
    i32x4 mN0 = mA0, mN1 = mA1;

    for(int kt=0; kt<64; kt++){
        const int cb = kt & 1;
        __syncthreads();   // drains staging + mask prefetch issued one body ago
        // ---- issue next-iteration memory FIRST (full body of latency slack) ----
        if(kt < 63){
            mN0 = ntload4(mp0 + (size_t)(kt+1)*64);
            mN1 = ntload4(mp0 + (size_t)16*4096 + (kt+1)*64);
            const unsigned char* gK = kfb + (size_t)(kt+1)*32768;
            const unsigned char* gV = vfb + (size_t)(kt+1)*32768;
            unsigned char* dst = smem + (cb^1)*65536;
            #pragma unroll
            for(int r=0; r<4; r++){
                glds16(gK + r*8192 + lsl, dst + r*8192 + ldd);
                glds16(gV + r*8192 + lsl, dst + 32768 + r*8192 + ldd);
            }
        }
        const unsigned short* bK = (const unsigned short*)(smem + cb*65536);
        const unsigned short* bV = (const unsigned short*)(smem + cb*65536 + 32768);

        // ---- S^T: D[n2local=4quad+r][q=lq] ----
        f32x4 sacc0 = (f32x4)(0.0f), sacc1 = (f32x4)(0.0f);
        #pragma unroll
        for(int ks=0; ks<8; ks++){
            s16x8 kf = *(const s16x8*)(bK + ((w*8 + ks)*64 + lane)*8);
            sacc0 = MFMA16(kf, qf[0][ks], sacc0);
            sacc1 = MFMA16(kf, qf[1][ks], sacc1);
        }
        // ---- mask + exp + pack (C rows 4quad+r == PV k=4quad+j) ----
        s16x4 pb0, pb1;
        {
            float p;
            p = (mA0.x>0)?__expf(sacc0[0]*0.0625f):1.0f; rsum[0]+=p; pb0[0]=(short)f2bf(p);
            p = (mA0.y>0)?__expf(sacc0[1]*0.0625f):1.0f; rsum[0]+=p; pb0[1]=(short)f2bf(p);
            p = (mA0.z>0)?__expf(sacc0[2]*0.0625f):1.0f; rsum[0]+=p; pb0[2]=(short)f2bf(p);
            p = (mA0.w>0)?__expf(sacc0[3]*0.0625f):1.0f; rsum[0]+=p; pb0[3]=(short)f2bf(p);
            p = (mA1.x>0)?__expf(sacc1[0]*0.0625f):1.0f; rsum[1]+=p; pb1[0]=(short)f2bf(p);
            p = (mA1.y>0)?__expf(sacc1[1]*0.0625f):1.0f; rsum[1]+=p; pb1[1]=(short)f2bf(p);
            p = (mA1.z>0)?__expf(sacc1[2]*0.0625f):1.0f; rsum[1]+=p; pb1[2]=(short)f2bf(p);
            p = (mA1.w>0)?__expf(sacc1[3]*0.0625f):1.0f; rsum[1]+=p; pb1[3]=(short)f2bf(p);
        }
        // ---- PV ----
        #pragma unroll
        for(int t2=0; t2<8; t2++){
            s16x8 vv = *(const s16x8*)(bV + ((w*8 + t2)*64 + lane)*8);
            s16x4 vlo = __builtin_shufflevector(vv, vv, 0,1,2,3);
            s16x4 vhi = __builtin_shufflevector(vv, vv, 4,5,6,7);
            oacc[2*t2  ][0] = mfma_pv(vlo, pb0, oacc[2*t2  ][0]);
            oacc[2*t2  ][1] = mfma_pv(vlo, pb1, oacc[2*t2  ][1]);
            oacc[2*t2+1][0] = mfma_pv(vhi, pb0, oacc[2*t2+1][0]);
            oacc[2*t2+1][1] = mfma_pv(vhi, pb1, oacc[2*t2+1][1]);
        }
        // rotate mask double-buffer
        mA0 = mN0; mA1 = mN1;
    }

    // ---- epilogue: alias buf0 region (safe: buf0 last read kt=62; all waves
    // past kt=63's barrier) ----
    float* sRS  = (float*)smem;              // [8][32]
    float* sRed = (float*)(smem + 1024);     // [4][2081]
    #pragma unroll
    for(int rg=0; rg<2; rg++){
        float v = rsum[rg];
        v += __shfl_xor(v, 16);
        v += __shfl_xor(v, 32);
        if(quad == 0) sRS[(qg*4 + w)*32 + 16*rg + lq] = v;
    }
    for(int g=0; g<2; g++){
        for(int c=0; c<4; c++){
            __syncthreads();
            if(qg == g){
                #pragma unroll
                for(int tt=0; tt<4; tt++){
                    int t = 4*c + tt;
                    #pragma unroll
                    for(int rg=0; rg<2; rg++){
                        #pragma unroll
                        for(int r=0; r<4; r++)
                            sRed[w*2081 + (16*rg+lq)*65 + 16*tt + 4*quad + r] = oacc[t][rg][r];
                    }
                }
            }
            __syncthreads();
            #pragma unroll
            for(int j=0; j<4; j++){
                int idx = j*512 + tid;
                int hl = idx & 63, q = idx >> 6;
                float s  = sRed[0*2081 + q*65+hl] + sRed[1*2081 + q*65+hl]
                         + sRed[2*2081 + q*65+hl] + sRed[3*2081 + q*65+hl];
                float rs = sRS[(g*4+0)*32+q] + sRS[(g*4+1)*32+q]
                         + sRS[(g*4+2)*32+q] + sRS[(g*4+3)*32+q];
                ntstoref(s / rs,
                    &out[((size_t)(b*4096 + qt*64 + 32*g + q))*256 + 64*c + hl]);
            }
        }
    }
}

extern "C" void kernel_launch(void* const* d_in, const int* in_sizes, int n_in,
                              void* d_out, int out_size, void* d_ws, size_t ws_size,
                              hipStream_t stream){
    (void)in_sizes; (void)n_in; (void)out_size;
    const float* x1 = (const float*)d_in[0];
    const float* x2 = (const float*)d_in[1];
    const int*   mk = (const int*)  d_in[2];
    const float* Wq = (const float*)d_in[3];
    const float* bq = (const float*)d_in[4];
    const float* Wk = (const float*)d_in[5];
    const float* bk = (const float*)d_in[6];
    const float* Wv = (const float*)d_in[7];
    const float* bv = (const float*)d_in[8];
    float* out = (float*)d_out;
    char* ws = (char*)d_ws;

    // ws layout: wt 384K @0 | q 8M | kfrag | vfrag
    unsigned short* wt = (unsigned short*)ws;
    unsigned short* qb = (unsigned short*)(ws + 393216);
    const size_t kvoff = 393216 + 8388608;

    wt_prep<<<dim3(32,3), 256, 0, stream>>>(Wq, Wk, Wv, wt);

    if(ws_size >= kvoff + 16ull*1024*1024){
        unsigned short* kf = (unsigned short*)(ws + kvoff);
        unsigned short* vf = (unsigned short*)(ws + kvoff + 8388608);
        proj_all<<<dim3(64,3,4), 256, 0, stream>>>(x1, x2, wt, bq, bk, bv, 0,
                                                   qb, kf, vf);
        attn<<<256, 512, 0, stream>>>(qb, kf, vf, mk, out, 0);
    } else {
        unsigned short* kf = (unsigned short*)(ws + kvoff);
        unsigned short* vf = (unsigned short*)(ws + kvoff + 2097152);
        for(int b=0;b<4;b++){
            proj_all<<<dim3(64,3,1), 256, 0, stream>>>(x1, x2, wt, bq, bk, bv, b,
                                                       qb, kf, vf);
            attn<<<64, 512, 0, stream>>>(qb, kf, vf, mk, out, b);
        }
    }
}